// Round 3
// baseline (189.537 us; speedup 1.0000x reference)
//
#include <hip/hip_runtime.h>

// EctLayer: ect[b,r,t] = sum_{n: batch[n]==b} sigmoid(SCALE*(lin[r] - (x[n]·dir[:,t])))
// N=65536, D=3, T=64, R=64, B=64. SCALE=500.
//
// Round-3 design: ZERO global atomics.
//  - batch is sorted: block b binary-searches its point range [lo,hi).
//  - saturation trick, single prefix-summable LDS array a[66][64]:
//      point with nearest-threshold index r0 and sigmoid value s adds
//        +s      at bin j1 = clamp(r0+1, 0, 65)
//        +(1-s)  at bin j2 = clamp(r0+2, 0, 65)
//      then out[r] = sum_{j<=r+1} a[j]  ==  {0 for r<r0, s at r0, 1 for r>r0}.
//    (bin 65 is a trash bin for points above all thresholds; clamped-low
//     points deposit s+(1-s)=1 at bin 0 -> counted everywhere, exact.)
//  - dropped tails are <= sigmoid(-8.73) = 1.6e-4 per point: worst-case
//    accumulated error ~0.2 vs threshold 19.44.
//  - flush once per block: 16-wave prefix sum over 66 rows, plain coalesced
//    stores of out[b,:,:]. No memset, no atomics, WRITE = 1 MB exactly.

#define T_DIRS   64
#define R_STEPS  64
#define N_BATCH  64
#define THREADS  1024
#define NWAVES   16
#define CHUNK    1024

#define RADIUS_F 1.1f
#define STEP_F   (2.0f * RADIUS_F / (R_STEPS - 1))          // 0.0349206
#define INV_STEP (1.0f / STEP_F)
#define OFF_F    (RADIUS_F * INV_STEP)                      // 31.5
#define MEXP     (-500.0f * STEP_F * 1.4426950408889634f)   // -K*log2(e)

__global__ __launch_bounds__(THREADS) void ect_kernel(
    const float* __restrict__ x,      // [N,3]
    const float* __restrict__ dirs,   // [3,T]
    const int*   __restrict__ batch,  // [N] sorted
    float* __restrict__ out,          // [B,R,T]
    int N)
{
    __shared__ float s_a[(R_STEPS + 2) * T_DIRS];   // 66 rows x 64 t = 16.9 KB
    __shared__ float s_x[CHUNK * 3];                // 12 KB
    __shared__ float s_wsum[NWAVES * T_DIRS];       // 4 KB

    const int tid = threadIdx.x;
    const int b   = blockIdx.x;
    const int t   = tid & (T_DIRS - 1);
    const int w   = tid >> 6;

    for (int i = tid; i < (R_STEPS + 2) * T_DIRS; i += THREADS) s_a[i] = 0.0f;

    // uniform binary searches (L2-cached, 16 steps each)
    int lo, hi;
    {
        int l = 0, h = N;
        while (l < h) { int m = (l + h) >> 1; if (batch[m] < b) l = m + 1; else h = m; }
        lo = l;
        h = N;
        while (l < h) { int m = (l + h) >> 1; if (batch[m] < b + 1) l = m + 1; else h = m; }
        hi = l;
    }

    const float d0 = dirs[t];
    const float d1 = dirs[T_DIRS + t];
    const float d2 = dirs[2 * T_DIRS + t];

    __syncthreads();

    for (int cbase = lo; cbase < hi; cbase += CHUNK) {
        const int cnt = min(CHUNK, hi - cbase);
        for (int i = tid; i < cnt * 3; i += THREADS) s_x[i] = x[cbase * 3 + i];
        __syncthreads();

        // each wave owns points p = w, w+16, ...; lane owns direction t
        for (int p = w; p < cnt; p += NWAVES) {
            float x0 = s_x[p * 3 + 0];              // uniform LDS -> broadcast
            float x1 = s_x[p * 3 + 1];
            float x2 = s_x[p * 3 + 2];
            float nh  = fmaf(x2, d2, fmaf(x1, d1, x0 * d0));
            float u   = fmaf(nh, INV_STEP, OFF_F);
            float r0f = floorf(u + 0.5f);
            float dd  = r0f - u;                              // [-0.5, 0.5]
            float e   = __builtin_amdgcn_exp2f(dd * MEXP);
            float s   = __builtin_amdgcn_rcpf(1.0f + e);      // sigmoid at r0
            int   r0  = (int)r0f;
            int   j1  = min(max(r0 + 1, 0), R_STEPS + 1);
            int   j2  = min(max(r0 + 2, 0), R_STEPS + 1);
            // bank = t&31 -> 2 lanes/bank (free, m136)
            atomicAdd(&s_a[j1 * T_DIRS + t], s);
            atomicAdd(&s_a[j2 * T_DIRS + t], 1.0f - s);
        }
        __syncthreads();
    }

    // flush: out[b,r,t] = sum_{j<=r+1} a[j][t]; wave w owns r in [4w, 4w+4)
    float ws = 0.0f;
#pragma unroll
    for (int i = 1; i <= 4; ++i) ws += s_a[(w * 4 + i) * T_DIRS + t];
    s_wsum[w * T_DIRS + t] = ws;
    __syncthreads();

    float run = s_a[t];                              // a[0]
    for (int w2 = 0; w2 < w; ++w2) run += s_wsum[w2 * T_DIRS + t];

    float* outb = out + b * (R_STEPS * T_DIRS);
#pragma unroll
    for (int i = 0; i < 4; ++i) {
        int r = w * 4 + i;
        run += s_a[(r + 1) * T_DIRS + t];
        outb[r * T_DIRS + t] = run;                  // plain coalesced store
    }
}

extern "C" void kernel_launch(void* const* d_in, const int* in_sizes, int n_in,
                              void* d_out, int out_size, void* d_ws, size_t ws_size,
                              hipStream_t stream) {
    const float* x     = (const float*)d_in[0];
    const float* dirs  = (const float*)d_in[1];
    const int*   batch = (const int*)d_in[3];
    float* out = (float*)d_out;
    const int N = in_sizes[3];

    dim3 grid(N_BATCH);
    dim3 block(THREADS);
    ect_kernel<<<grid, block, 0, stream>>>(x, dirs, batch, out, N);
}

// Round 4
// 19.718 us; speedup vs baseline: 9.6126x; 9.6126x over previous
//
#include <hip/hip_runtime.h>

// EctLayer: ect[b,r,t] = sum_{n: batch[n]==b} sigmoid(SCALE*(lin[r] - (x[n]·dir[:,t])))
// N=65536, D=3, T=64, R=64, B=64. SCALE=500.
//
// Round-4: NO floating-point atomics anywhere (hipcc compiles f32 atomicAdd to
// a ~220-cyc CAS loop — measured r2/r3). Fixed-point integer histogram:
//   point (u = (nh+R)/step, r0 = round(u), s = sigmoid at r0, si = round(s*2^16)):
//     ds_add_u32  +si          at bin j1 = clamp(r0+1, 0, 65)
//     ds_add_u32  +(2^16-si)   at bin j2 = clamp(r0+2, 0, 65)
//   out[r] = (sum_{j<=r+1} bins[j]) / 2^16  == {0 below r0, s at r0, 1 above}.
// Mass is exact (si + (2^16-si) = 2^16); quantization error <= 0.008/cell;
// saturation-tail drop <= ~0.2/cell worst case (threshold 19.44).
//
// 3 dispatches: K0 offsets (boundary scan) -> K1 bins (B*S=256 blocks, LDS
// integer histogram, u32 prefix, f32 partial to ws) -> K2 reduce (sum S
// partials -> out). Fallback single-kernel path if ws_size too small.

#define T_DIRS   64
#define R_STEPS  64
#define N_BATCH  64
#define NBINS    (R_STEPS + 2)          // 66
#define SPLITS   4
#define THREADS  1024
#define NWAVES   16

#define RADIUS_F 1.1f
#define STEP_F   (2.0f * RADIUS_F / (R_STEPS - 1))
#define INV_STEP (1.0f / STEP_F)
#define OFF_F    (RADIUS_F * INV_STEP)                      // 31.5
#define MEXP     (-500.0f * STEP_F * 1.4426950408889634f)   // -K*log2(e)
#define FIXP     65536.0f
#define INV_FIXP (1.0f / 65536.0f)

// ---- K0: offsets[b] = lower_bound(batch, b), b in [0,64] --------------------
__global__ __launch_bounds__(256) void offsets_kernel(
    const int* __restrict__ batch, int N, unsigned* __restrict__ off)
{
    int i = blockIdx.x * 256 + threadIdx.x;
    if (i >= N) return;
    int v  = batch[i];
    int vp = (i == 0) ? -1 : batch[i - 1];
    for (int b = vp + 1; b <= v; ++b) off[b] = (unsigned)i;        // boundaries
    if (i == N - 1)
        for (int b = v + 1; b <= N_BATCH; ++b) off[b] = (unsigned)N;
}

// ---- shared device body: accumulate [lo,hi) into u32 bins, prefix, emit ----
__device__ __forceinline__ void ect_accum_flush(
    const float* __restrict__ x, const float* __restrict__ dirs,
    unsigned lo, unsigned hi, float* __restrict__ dst /* [R*T] */)
{
    __shared__ unsigned s_a[NBINS * T_DIRS];     // 16.9 KB
    __shared__ unsigned s_ws[NWAVES * T_DIRS];   // 4 KB

    const int tid = threadIdx.x;
    const int t   = tid & (T_DIRS - 1);
    const int w   = tid >> 6;

    for (int i = tid; i < NBINS * T_DIRS; i += THREADS) s_a[i] = 0u;

    const float d0 = dirs[t];
    const float d1 = dirs[T_DIRS + t];
    const float d2 = dirs[2 * T_DIRS + t];
    __syncthreads();

    for (unsigned p = lo + w; p < hi; p += NWAVES) {
        float x0 = x[p * 3 + 0];                 // wave-uniform addr, L1/L2
        float x1 = x[p * 3 + 1];
        float x2 = x[p * 3 + 2];
        float nh  = fmaf(x2, d2, fmaf(x1, d1, x0 * d0));
        float u   = fmaf(nh, INV_STEP, OFF_F);
        float r0f = floorf(u + 0.5f);
        float dd  = r0f - u;                               // [-0.5, 0.5]
        float e   = __builtin_amdgcn_exp2f(dd * MEXP);
        float s   = __builtin_amdgcn_rcpf(1.0f + e);       // sigmoid at r0
        unsigned si = (unsigned)(fmaf(s, FIXP, 0.5f));     // [0, 65536]
        int r0 = (int)r0f;
        int j1 = min(max(r0 + 1, 0), R_STEPS + 1);
        int j2 = min(max(r0 + 2, 0), R_STEPS + 1);
        // bank = t&31: 2 lanes/bank, distinct addresses -> conflict-free-ish
        atomicAdd(&s_a[j1 * T_DIRS + t], si);              // native ds_add_u32
        atomicAdd(&s_a[j2 * T_DIRS + t], 65536u - si);
    }
    __syncthreads();

    // exact u32 prefix over bins: out[r] = sum_{j<=r+1} a[j]
    unsigned wsum = 0;
#pragma unroll
    for (int i = 1; i <= 4; ++i) wsum += s_a[(w * 4 + i) * T_DIRS + t];
    s_ws[w * T_DIRS + t] = wsum;
    __syncthreads();

    unsigned run = s_a[t];                                 // bin 0
    for (int w2 = 0; w2 < w; ++w2) run += s_ws[w2 * T_DIRS + t];
#pragma unroll
    for (int i = 0; i < 4; ++i) {
        int r = w * 4 + i;
        run += s_a[(r + 1) * T_DIRS + t];
        dst[r * T_DIRS + t] = (float)run * INV_FIXP;       // plain store
    }
}

// ---- K1: block = (b, split); partial -> ws ---------------------------------
__global__ __launch_bounds__(THREADS) void bins_kernel(
    const float* __restrict__ x, const float* __restrict__ dirs,
    const unsigned* __restrict__ off, float* __restrict__ part)
{
    const int b  = blockIdx.x >> 2;
    const int sp = blockIdx.x & (SPLITS - 1);
    unsigned lo = off[b], hi = off[b + 1];
    unsigned len = hi - lo;
    unsigned slo = lo + (len * (unsigned)sp) / SPLITS;
    unsigned shi = lo + (len * (unsigned)(sp + 1)) / SPLITS;
    ect_accum_flush(x, dirs, slo, shi, part + (size_t)blockIdx.x * (R_STEPS * T_DIRS));
}

// ---- K2: out[b] = sum_s part[b*S+s] ----------------------------------------
__global__ __launch_bounds__(256) void reduce_kernel(
    const float* __restrict__ part, float* __restrict__ out)
{
    int idx = (blockIdx.x * 256 + threadIdx.x) * 4;        // over B*R*T
    int b     = idx >> 12;                                 // /4096
    int inner = idx & 4095;
    float4 acc = *(const float4*)&part[(size_t)(b * SPLITS) * 4096 + inner];
#pragma unroll
    for (int s = 1; s < SPLITS; ++s) {
        float4 v = *(const float4*)&part[(size_t)(b * SPLITS + s) * 4096 + inner];
        acc.x += v.x; acc.y += v.y; acc.z += v.z; acc.w += v.w;
    }
    *(float4*)&out[idx] = acc;
}

// ---- fallback: single kernel, per-batch block, in-kernel binary search -----
__global__ __launch_bounds__(THREADS) void direct_kernel(
    const float* __restrict__ x, const float* __restrict__ dirs,
    const int* __restrict__ batch, int N, float* __restrict__ out)
{
    const int b = blockIdx.x;
    int l = 0, h = N;
    while (l < h) { int m = (l + h) >> 1; if (batch[m] < b) l = m + 1; else h = m; }
    unsigned lo = l; h = N;
    while (l < h) { int m = (l + h) >> 1; if (batch[m] < b + 1) l = m + 1; else h = m; }
    unsigned hi = l;
    ect_accum_flush(x, dirs, lo, hi, out + (size_t)b * (R_STEPS * T_DIRS));
}

extern "C" void kernel_launch(void* const* d_in, const int* in_sizes, int n_in,
                              void* d_out, int out_size, void* d_ws, size_t ws_size,
                              hipStream_t stream) {
    const float* x     = (const float*)d_in[0];
    const float* dirs  = (const float*)d_in[1];
    const int*   batch = (const int*)d_in[3];
    float* out = (float*)d_out;
    const int N = in_sizes[3];

    const size_t part_bytes = (size_t)N_BATCH * SPLITS * R_STEPS * T_DIRS * sizeof(float);
    const size_t need = 4096 + part_bytes;   // offsets (pad 4 KB) + partials

    if (ws_size >= need) {
        unsigned* off  = (unsigned*)d_ws;
        float*    part = (float*)((char*)d_ws + 4096);
        offsets_kernel<<<dim3((N + 255) / 256), dim3(256), 0, stream>>>(batch, N, off);
        bins_kernel<<<dim3(N_BATCH * SPLITS), dim3(THREADS), 0, stream>>>(x, dirs, off, part);
        reduce_kernel<<<dim3((N_BATCH * R_STEPS * T_DIRS) / 1024), dim3(256), 0, stream>>>(part, out);
    } else {
        direct_kernel<<<dim3(N_BATCH), dim3(THREADS), 0, stream>>>(x, dirs, batch, N, out);
    }
}